// Round 5
// baseline (382.967 us; speedup 1.0000x reference)
//
#include <hip/hip_runtime.h>

#define NNODES 10000
#define NEDGES 160000
#define MPAD   10240      // 40 * 256
#define FIN    768
#define D2     1024
#define D2X2   2048
#define TSTEPS 50

typedef __bf16 bf16x8 __attribute__((ext_vector_type(8)));
typedef float  f32x4  __attribute__((ext_vector_type(4)));

__device__ __forceinline__ unsigned short f2bf(float f) {
    unsigned u = __builtin_bit_cast(unsigned, f);
    u += 0x7FFFu + ((u >> 16) & 1u);
    return (unsigned short)(u >> 16);
}
__device__ __forceinline__ void unpk(unsigned u, float& a, float& b) {
    a = __builtin_bit_cast(float, u << 16);
    b = __builtin_bit_cast(float, u & 0xFFFF0000u);
}
__device__ __forceinline__ void gload16(const void* g, void* l) {
    __builtin_amdgcn_global_load_lds((const __attribute__((address_space(1))) void*)g,
                                     (__attribute__((address_space(3))) void*)l, 16, 0, 0);
}

// ---------------- CSR: count ----------------
__global__ void csr_count(const int* __restrict__ ei, int* cnt) {
    int g = blockIdx.x * 256 + threadIdx.x;
    if (g < NEDGES) atomicAdd(&cnt[ei[NEDGES + g]], 1);
}
// ---------------- CSR: scan (+ cosine schedule fold-in) ----------------
__global__ void csr_scan(const int* __restrict__ cnt, int* rowp, int* cur, float* sched) {
    if (threadIdx.x == 0) {
        const double PI = 3.14159265358979323846;
        double acp = 1.0;
        for (int i = 0; i < TSTEPS; ++i) {
            double x0 = (double)i / (double)TSTEPS;
            double x1 = (double)(i + 1) / (double)TSTEPS;
            double c0 = cos((x0 + 0.008) / 1.008 * PI * 0.5);
            double c1 = cos((x1 + 0.008) / 1.008 * PI * 0.5);
            double a0 = c0 * c0, a1 = c1 * c1;
            double beta = 1.0 - a1 / a0;
            if (beta < 0.0) beta = 0.0;
            if (beta > 0.999) beta = 0.999;
            acp *= (1.0 - beta);
            sched[i]      = (float)sqrt(acp);
            sched[64 + i] = (float)sqrt(1.0 - acp);
        }
    }
    __shared__ int part[1024];
    int tid = threadIdx.x;
    const int per = 10;
    int base = tid * per;
    int local[per];
    int s = 0;
    #pragma unroll
    for (int i = 0; i < per; ++i) {
        int idx = base + i;
        int v = (idx < NNODES) ? (cnt[idx] + 1) : 0;   // +1 = self loop
        local[i] = s;
        s += v;
    }
    part[tid] = s;
    __syncthreads();
    for (int off = 1; off < 1024; off <<= 1) {
        int v = (tid >= off) ? part[tid - off] : 0;
        __syncthreads();
        part[tid] += v;
        __syncthreads();
    }
    int offset = (tid > 0) ? part[tid - 1] : 0;
    #pragma unroll
    for (int i = 0; i < per; ++i) {
        int idx = base + i;
        if (idx < NNODES) {
            int v = offset + local[i];
            rowp[idx] = v;
            cur[idx]  = v;
        } else if (idx == NNODES) {
            rowp[NNODES] = offset + local[i];
        }
    }
}
// ---------------- CSR: fill ----------------
__global__ void csr_fill(const int* __restrict__ ei, const int* __restrict__ rowp,
                         int* cur, int* colv) {
    int g = blockIdx.x * 256 + threadIdx.x;
    if (g < NEDGES) {
        int s = ei[g];
        int d = ei[NEDGES + g];
        int pos = atomicAdd(&cur[d], 1);
        colv[pos] = s;
    } else if (g < NEDGES + NNODES) {
        int d = g - NEDGES;
        colv[rowp[d + 1] - 1] = d;
    }
}

// ---------------- weight pack: fp32 W[K][N] -> bf16 MFMA B-fragments ----------------
// chunk (n16, k32): 64 lanes x 16B; lane kq*16+lr holds B[col=n16*16+lr][k=k32*32+kq*8+j]
struct PJ { const float* W; unsigned short* out; int K; int N; int n16off; int end; };
struct PJ5 { PJ j[5]; };
__global__ void __launch_bounds__(256)
pack_w(PJ5 js) {
    int b = blockIdx.x;
    int i = 0;
    #pragma unroll
    for (int k = 0; k < 5; ++k) if (b >= js.j[k].end) i = k + 1;
    PJ p = js.j[i];
    int start = (i > 0) ? js.j[i - 1].end : 0;
    int lb = b - start;
    int kblocks = p.K >> 5;
    int kb = lb % kblocks;
    int nb = lb / kblocks;
    __shared__ float tile[32][65];
    const int tid = threadIdx.x;
    #pragma unroll
    for (int q = 0; q < 8; ++q) {
        int idx = tid + q * 256;
        int row = idx >> 6, col = idx & 63;
        tile[row][col] = p.W[(size_t)(kb * 32 + row) * p.N + nb * 64 + col];
    }
    __syncthreads();
    const int grp = tid >> 6;
    const int lane = tid & 63;
    const int lr = lane & 15, kq = lane >> 4;
    unsigned wv[4];
    #pragma unroll
    for (int q = 0; q < 4; ++q) {
        float a = tile[kq * 8 + 2 * q][grp * 16 + lr];
        float c = tile[kq * 8 + 2 * q + 1][grp * 16 + lr];
        wv[q] = (unsigned)f2bf(a) | ((unsigned)f2bf(c) << 16);
    }
    int n16 = p.n16off + nb * 4 + grp;
    unsigned short* dst = p.out + ((size_t)n16 * kblocks + kb) * 512 + lane * 8;
    uint4 s; s.x = wv[0]; s.y = wv[1]; s.z = wv[2]; s.w = wv[3];
    *(uint4*)dst = s;
}

// ---------------- diffusion noise add -> bf16 ----------------
__global__ void x0_kernel(const float* __restrict__ emb, const float* __restrict__ noise,
                          const int* __restrict__ t, const float* __restrict__ sched,
                          unsigned short* __restrict__ x0b) {
    int i4 = blockIdx.x * 256 + threadIdx.x;
    if (i4 >= MPAD * (FIN / 4)) return;
    int row = i4 / (FIN / 4);
    int c = (i4 % (FIN / 4)) * 4;
    unsigned short* dst = x0b + (size_t)row * FIN + c;
    if (row < NNODES) {
        int tv = t[row];
        float sa = sched[tv], so = sched[64 + tv];
        float4 e = *(const float4*)(emb + (size_t)row * FIN + c);
        float4 nz = *(const float4*)(noise + (size_t)row * FIN + c);
        float v0 = sa * e.x + so * nz.x;
        float v1 = sa * e.y + so * nz.y;
        float v2 = sa * e.z + so * nz.z;
        float v3 = sa * e.w + so * nz.w;
        uint2 pk;
        pk.x = (unsigned)f2bf(v0) | ((unsigned)f2bf(v1) << 16);
        pk.y = (unsigned)f2bf(v2) | ((unsigned)f2bf(v3) << 16);
        *(uint2*)dst = pk;
    } else {
        uint2 pk; pk.x = 0u; pk.y = 0u;
        *(uint2*)dst = pk;
    }
}

// ---------------- bf16 MFMA GEMM: A via LDS (dbuf), B via packed-fragment global ----------------
template<bool OUT_BF16>
__global__ void __launch_bounds__(256, 2)
gemmW(const unsigned short* __restrict__ A, const unsigned short* __restrict__ Bp,
      const float* __restrict__ bl, const float* __restrict__ br, void* __restrict__ C,
      int K, int Nn, int Mstore, int gy) {
    __shared__ __align__(16) unsigned short As[2][256 * 64];   // 64 KB

    const int tid = threadIdx.x;
    const int lane = tid & 63;
    const int wv = tid >> 6;
    const int wm = wv >> 1;
    const int wn = wv & 1;
    const int lr = lane & 15;
    const int kq = lane >> 4;
    const int K32 = K >> 5;

    const int total = gridDim.x;
    int lin = blockIdx.x;
    int q = total >> 3, r = total & 7;
    int xcd = lin & 7, idx = lin >> 3;
    int lin2 = (xcd < r ? xcd * (q + 1) : r * (q + 1) + (xcd - r) * q) + idx;
    const int rowBase = (lin2 / gy) * 256;
    const int colBase = (lin2 % gy) * 128;

    f32x4 acc[8][4];
    #pragma unroll
    for (int m = 0; m < 8; ++m)
        #pragma unroll
        for (int n = 0; n < 4; ++n)
            acc[m][n] = (f32x4){0.f, 0.f, 0.f, 0.f};

    const int r8 = tid >> 3;
    const int cb = (tid & 7) * 16;
    const size_t Kb = (size_t)K * 2;

    auto stageA = [&](int buf, int kt) {
        #pragma unroll
        for (int i = 0; i < 8; ++i) {
            int rr = i * 32 + r8;
            int scb = cb ^ ((rr & 7) << 4);
            gload16((const char*)A + (size_t)(rowBase + rr) * Kb + (size_t)kt * 2 + scb,
                    (char*)&As[buf][0] + rr * 128 + cb);
        }
    };
    const int n16b = (colBase >> 4) + wn * 4;
    auto loadB = [&](int k32, bf16x8* dst) {
        #pragma unroll
        for (int n = 0; n < 4; ++n)
            dst[n] = *(const bf16x8*)(Bp + ((size_t)(n16b + n) * K32 + k32) * 512 + lane * 8);
    };

    const int NT = K >> 6;
    bf16x8 fb0[4], fb1[4];
    stageA(0, 0);
    loadB(0, fb0);
    stageA(1, 64);

    for (int t = 0; t < NT; ++t) {
        if (t == 0)           asm volatile("s_waitcnt vmcnt(12)" ::: "memory");
        else if (t == NT - 1) asm volatile("s_waitcnt vmcnt(8)"  ::: "memory");
        else                  asm volatile("s_waitcnt vmcnt(16)" ::: "memory");
        __builtin_amdgcn_s_barrier();
        __builtin_amdgcn_sched_barrier(0);

        loadB(t * 2 + 1, fb1);                       // fb(t).k2=1
        __builtin_amdgcn_sched_barrier(0);

        const char* la = (const char*)&As[t & 1][0];
        bf16x8 fa[8];
        #pragma unroll
        for (int m = 0; m < 8; ++m) {
            int fr = wm * 128 + m * 16 + lr;
            fa[m] = *(const bf16x8*)(la + ((fr * 128 + kq * 16) ^ ((fr & 7) << 4)));
        }
        __builtin_amdgcn_s_setprio(1);
        #pragma unroll
        for (int m = 0; m < 8; ++m) {
            acc[m][0] = __builtin_amdgcn_mfma_f32_16x16x32_bf16(fa[m], fb0[0], acc[m][0], 0, 0, 0);
            acc[m][1] = __builtin_amdgcn_mfma_f32_16x16x32_bf16(fa[m], fb0[1], acc[m][1], 0, 0, 0);
            acc[m][2] = __builtin_amdgcn_mfma_f32_16x16x32_bf16(fa[m], fb0[2], acc[m][2], 0, 0, 0);
            acc[m][3] = __builtin_amdgcn_mfma_f32_16x16x32_bf16(fa[m], fb0[3], acc[m][3], 0, 0, 0);
        }
        __builtin_amdgcn_s_setprio(0);
        __builtin_amdgcn_sched_barrier(0);
        if (t + 1 < NT) loadB((t + 1) * 2, fb0);     // fb(t+1).k2=0
        __builtin_amdgcn_sched_barrier(0);

        #pragma unroll
        for (int m = 0; m < 8; ++m) {
            int fr = wm * 128 + m * 16 + lr;
            fa[m] = *(const bf16x8*)(la + ((fr * 128 + 64 + kq * 16) ^ ((fr & 7) << 4)));
        }
        asm volatile("s_waitcnt lgkmcnt(0)" ::: "memory");
        __builtin_amdgcn_sched_barrier(0);
        __builtin_amdgcn_s_barrier();                // all waves done reading As[t&1]
        __builtin_amdgcn_sched_barrier(0);
        if (t + 2 < NT) stageA(t & 1, (t + 2) * 64);
        __builtin_amdgcn_sched_barrier(0);
        __builtin_amdgcn_s_setprio(1);
        #pragma unroll
        for (int m = 0; m < 8; ++m) {
            acc[m][0] = __builtin_amdgcn_mfma_f32_16x16x32_bf16(fa[m], fb1[0], acc[m][0], 0, 0, 0);
            acc[m][1] = __builtin_amdgcn_mfma_f32_16x16x32_bf16(fa[m], fb1[1], acc[m][1], 0, 0, 0);
            acc[m][2] = __builtin_amdgcn_mfma_f32_16x16x32_bf16(fa[m], fb1[2], acc[m][2], 0, 0, 0);
            acc[m][3] = __builtin_amdgcn_mfma_f32_16x16x32_bf16(fa[m], fb1[3], acc[m][3], 0, 0, 0);
        }
        __builtin_amdgcn_s_setprio(0);
        __builtin_amdgcn_sched_barrier(0);
    }

    #pragma unroll
    for (int n = 0; n < 4; ++n) {
        int col = colBase + wn * 64 + n * 16 + lr;
        float bcol = (col < D2) ? bl[col] : br[col - D2];
        #pragma unroll
        for (int m = 0; m < 8; ++m) {
            int row0 = rowBase + wm * 128 + m * 16 + kq * 4;
            #pragma unroll
            for (int j = 0; j < 4; ++j) {
                float v = acc[m][n][j] + bcol;
                if (OUT_BF16) {
                    ((unsigned short*)C)[(size_t)(row0 + j) * Nn + col] = f2bf(v);
                } else {
                    if (row0 + j < Mstore)
                        ((float*)C)[(size_t)(row0 + j) * Nn + col] = v;
                }
            }
        }
    }
}

// ---------------- GATv2 attention: one wave per destination node ----------------
__global__ void __launch_bounds__(256)
attn_kernel(const unsigned short* __restrict__ xlr,
            const int* __restrict__ rowp, const int* __restrict__ colv,
            const float* __restrict__ att, const float* __restrict__ bias,
            unsigned short* __restrict__ out) {
    const int lane = threadIdx.x & 63;
    const int node = blockIdx.x * 4 + (threadIdx.x >> 6);
    const int j0 = lane * 16;

    if (node >= NNODES) {
        if (node < MPAD) {
            uint4 z; z.x = z.y = z.z = z.w = 0u;
            *(uint4*)(out + (size_t)node * D2 + j0) = z;
            *(uint4*)(out + (size_t)node * D2 + j0 + 8) = z;
        }
        return;
    }

    float attv[16], xrv[16];
    #pragma unroll
    for (int q = 0; q < 4; ++q) {
        float4 t4 = *(const float4*)(att + j0 + q * 4);
        attv[4 * q] = t4.x; attv[4 * q + 1] = t4.y; attv[4 * q + 2] = t4.z; attv[4 * q + 3] = t4.w;
    }
    {
        const unsigned short* xr = xlr + (size_t)node * D2X2 + D2 + j0;
        uint4 v0 = *(const uint4*)(xr);
        uint4 v1 = *(const uint4*)(xr + 8);
        unsigned u[8] = {v0.x, v0.y, v0.z, v0.w, v1.x, v1.y, v1.z, v1.w};
        #pragma unroll
        for (int q = 0; q < 8; ++q) unpk(u[q], xrv[2 * q], xrv[2 * q + 1]);
    }

    float acc[16];
    #pragma unroll
    for (int q = 0; q < 16; ++q) acc[q] = 0.f;
    float mbase = 8.0f;
    float lsum = 0.f;

    const int p0 = rowp[node], p1 = rowp[node + 1];

    int sA = colv[p0];
    int sB = (p0 + 1 < p1) ? colv[p0 + 1] : sA;
    uint4 a0 = *(const uint4*)(xlr + (size_t)sA * D2X2 + j0);
    uint4 a1 = *(const uint4*)(xlr + (size_t)sA * D2X2 + j0 + 8);
    uint4 b0 = *(const uint4*)(xlr + (size_t)sB * D2X2 + j0);
    uint4 b1 = *(const uint4*)(xlr + (size_t)sB * D2X2 + j0 + 8);

    for (int p = p0; p < p1; ++p) {
        int sN = (p + 2 < p1) ? colv[p + 2] : sA;
        uint4 f0 = *(const uint4*)(xlr + (size_t)sN * D2X2 + j0);
        uint4 f1 = *(const uint4*)(xlr + (size_t)sN * D2X2 + j0 + 8);

        float xs[16];
        {
            unsigned u[8] = {a0.x, a0.y, a0.z, a0.w, a1.x, a1.y, a1.z, a1.w};
            #pragma unroll
            for (int q = 0; q < 8; ++q) unpk(u[q], xs[2 * q], xs[2 * q + 1]);
        }

        float part = 0.f;
        #pragma unroll
        for (int q = 0; q < 16; ++q) {
            float v = xs[q] + xrv[q];
            v = fmaxf(v, 0.2f * v);
            part += v * attv[q];
        }
        part += __shfl_xor(part, 1);
        part += __shfl_xor(part, 2);
        part += __shfl_xor(part, 4);
        part += __shfl_xor(part, 8);

        if (__builtin_expect(part > mbase, 0)) {
            float sc = __expf(mbase - part);
            lsum *= sc;
            #pragma unroll
            for (int q = 0; q < 16; ++q) acc[q] *= sc;
            mbase = part;
        }
        float pw = __expf(part - mbase);
        lsum += pw;
        #pragma unroll
        for (int q = 0; q < 16; ++q) acc[q] += pw * xs[q];

        a0 = b0; a1 = b1; b0 = f0; b1 = f1;
    }

    float inv = 1.f / lsum;
    unsigned w[8];
    #pragma unroll
    for (int q = 0; q < 8; ++q) {
        float o0 = acc[2 * q] * inv + bias[j0 + 2 * q];
        float o1 = acc[2 * q + 1] * inv + bias[j0 + 2 * q + 1];
        o0 = (o0 > 0.f) ? o0 : (__expf(o0) - 1.f);
        o1 = (o1 > 0.f) ? o1 : (__expf(o1) - 1.f);
        w[q] = (unsigned)f2bf(o0) | ((unsigned)f2bf(o1) << 16);
    }
    uint4 v0, v1;
    v0.x = w[0]; v0.y = w[1]; v0.z = w[2]; v0.w = w[3];
    v1.x = w[4]; v1.y = w[5]; v1.z = w[6]; v1.w = w[7];
    *(uint4*)(out + (size_t)node * D2 + j0) = v0;
    *(uint4*)(out + (size_t)node * D2 + j0 + 8) = v1;
}

// ---------------- host launch ----------------
extern "C" void kernel_launch(void* const* d_in, const int* in_sizes, int n_in,
                              void* d_out, int out_size, void* d_ws, size_t ws_size,
                              hipStream_t stream) {
    const float* emb   = (const float*)d_in[0];
    const float* noise = (const float*)d_in[1];
    const int*   tarr  = (const int*)d_in[2];
    const int*   ei    = (const int*)d_in[3];
    const float* Wl1   = (const float*)d_in[4];
    const float* bl1   = (const float*)d_in[5];
    const float* Wr1   = (const float*)d_in[6];
    const float* br1   = (const float*)d_in[7];
    const float* att1  = (const float*)d_in[8];
    const float* bias1 = (const float*)d_in[9];
    const float* Wl2   = (const float*)d_in[10];
    const float* bl2   = (const float*)d_in[11];
    const float* Wr2   = (const float*)d_in[12];
    const float* br2   = (const float*)d_in[13];
    const float* att2  = (const float*)d_in[14];
    const float* bias2 = (const float*)d_in[15];
    const float* Wout  = (const float*)d_in[16];
    const float* bout  = (const float*)d_in[17];
    float* out = (float*)d_out;

    char* wsp = (char*)d_ws;
    size_t off = 0;
    auto carve = [&](size_t b) -> void* {
        void* p = wsp + off;
        off = (off + b + 255) & ~(size_t)255;
        return p;
    };
    float* sched = (float*)carve(128 * 4);
    int* cnt  = (int*)carve(NNODES * 4);
    int* rowp = (int*)carve((NNODES + 1) * 4);
    int* cur  = (int*)carve(NNODES * 4);
    int* colv = (int*)carve((NEDGES + NNODES) * 4);
    unsigned short* x0b  = (unsigned short*)carve((size_t)MPAD * FIN * 2);
    unsigned short* xlrb = (unsigned short*)carve((size_t)MPAD * D2X2 * 2);
    unsigned short* hb   = (unsigned short*)carve((size_t)MPAD * D2 * 2);
    unsigned short* Bp1  = (unsigned short*)carve((size_t)D2X2 * FIN * 2);
    unsigned short* Bp2  = (unsigned short*)carve((size_t)D2X2 * D2 * 2);
    unsigned short* Bpo  = (unsigned short*)carve((size_t)FIN * D2 * 2);

    hipMemsetAsync(cnt, 0, NNODES * 4, stream);
    csr_count<<<(NEDGES + 255) / 256, 256, 0, stream>>>(ei, cnt);
    csr_scan<<<1, 1024, 0, stream>>>(cnt, rowp, cur, sched);
    csr_fill<<<(NEDGES + NNODES + 255) / 256, 256, 0, stream>>>(ei, rowp, cur, colv);

    {
        PJ5 js;
        js.j[0] = {Wl1, Bp1, FIN, D2, 0, 384};
        js.j[1] = {Wr1, Bp1, FIN, D2, 64, 768};
        js.j[2] = {Wl2, Bp2, D2, D2, 0, 1280};
        js.j[3] = {Wr2, Bp2, D2, D2, 64, 1792};
        js.j[4] = {Wout, Bpo, D2, FIN, 0, 2176};
        pack_w<<<2176, 256, 0, stream>>>(js);
    }

    x0_kernel<<<(MPAD * (FIN / 4)) / 256, 256, 0, stream>>>(emb, noise, tarr, sched, x0b);

    gemmW<true><<<dim3((MPAD / 256) * (D2X2 / 128)), 256, 0, stream>>>(
        x0b, Bp1, bl1, br1, xlrb, FIN, D2X2, MPAD, D2X2 / 128);
    attn_kernel<<<MPAD / 4, 256, 0, stream>>>(xlrb, rowp, colv, att1, bias1, hb);

    gemmW<true><<<dim3((MPAD / 256) * (D2X2 / 128)), 256, 0, stream>>>(
        hb, Bp2, bl2, br2, xlrb, D2, D2X2, MPAD, D2X2 / 128);
    attn_kernel<<<MPAD / 4, 256, 0, stream>>>(xlrb, rowp, colv, att2, bias2, hb);

    gemmW<false><<<dim3((MPAD / 256) * (FIN / 128)), 256, 0, stream>>>(
        hb, Bpo, bout, bout, out, D2, FIN, NNODES, FIN / 128);

    (void)in_sizes; (void)n_in; (void)out_size; (void)ws_size;
}

// Round 6
// 363.993 us; speedup vs baseline: 1.0521x; 1.0521x over previous
//
#include <hip/hip_runtime.h>

#define NNODES 10000
#define NEDGES 160000
#define MPAD   10240      // 40 * 256
#define FIN    768
#define D2     1024
#define D2X2   2048
#define TSTEPS 50

#define RING_STRIDE 49152          // A 32KB + B 16KB per ring slot
#define LDS_BYTES   147456         // 3 ring slots

typedef __bf16 bf16x8 __attribute__((ext_vector_type(8)));
typedef float  f32x4  __attribute__((ext_vector_type(4)));
typedef float  f32x2  __attribute__((ext_vector_type(2)));

__device__ __forceinline__ unsigned short f2bf(float f) {
    unsigned u = __builtin_bit_cast(unsigned, f);
    u += 0x7FFFu + ((u >> 16) & 1u);
    return (unsigned short)(u >> 16);
}
__device__ __forceinline__ f32x2 unpk2(unsigned u) {
    f32x2 r;
    r.x = __builtin_bit_cast(float, u << 16);
    r.y = __builtin_bit_cast(float, u & 0xFFFF0000u);
    return r;
}
__device__ __forceinline__ void gload16(const void* g, void* l) {
    __builtin_amdgcn_global_load_lds((const __attribute__((address_space(1))) void*)g,
                                     (__attribute__((address_space(3))) void*)l, 16, 0, 0);
}

// ---------------- CSR: count ----------------
__global__ void csr_count(const int* __restrict__ ei, int* cnt) {
    int g = blockIdx.x * 256 + threadIdx.x;
    if (g < NEDGES) atomicAdd(&cnt[ei[NEDGES + g]], 1);
}
// ---------------- CSR: scan (+ cosine schedule fold-in) ----------------
__global__ void csr_scan(const int* __restrict__ cnt, int* rowp, int* cur, float* sched) {
    if (threadIdx.x == 0) {
        const double PI = 3.14159265358979323846;
        double acp = 1.0;
        for (int i = 0; i < TSTEPS; ++i) {
            double x0 = (double)i / (double)TSTEPS;
            double x1 = (double)(i + 1) / (double)TSTEPS;
            double c0 = cos((x0 + 0.008) / 1.008 * PI * 0.5);
            double c1 = cos((x1 + 0.008) / 1.008 * PI * 0.5);
            double a0 = c0 * c0, a1 = c1 * c1;
            double beta = 1.0 - a1 / a0;
            if (beta < 0.0) beta = 0.0;
            if (beta > 0.999) beta = 0.999;
            acp *= (1.0 - beta);
            sched[i]      = (float)sqrt(acp);
            sched[64 + i] = (float)sqrt(1.0 - acp);
        }
    }
    __shared__ int part[1024];
    int tid = threadIdx.x;
    const int per = 10;
    int base = tid * per;
    int local[per];
    int s = 0;
    #pragma unroll
    for (int i = 0; i < per; ++i) {
        int idx = base + i;
        int v = (idx < NNODES) ? (cnt[idx] + 1) : 0;   // +1 = self loop
        local[i] = s;
        s += v;
    }
    part[tid] = s;
    __syncthreads();
    for (int off = 1; off < 1024; off <<= 1) {
        int v = (tid >= off) ? part[tid - off] : 0;
        __syncthreads();
        part[tid] += v;
        __syncthreads();
    }
    int offset = (tid > 0) ? part[tid - 1] : 0;
    #pragma unroll
    for (int i = 0; i < per; ++i) {
        int idx = base + i;
        if (idx < NNODES) {
            int v = offset + local[i];
            rowp[idx] = v;
            cur[idx]  = v;
        } else if (idx == NNODES) {
            rowp[NNODES] = offset + local[i];
        }
    }
}
// ---------------- CSR: fill (self loop at fixed last slot) ----------------
__global__ void csr_fill(const int* __restrict__ ei, const int* __restrict__ rowp,
                         int* cur, int* colv) {
    int g = blockIdx.x * 256 + threadIdx.x;
    if (g < NEDGES) {
        int s = ei[g];
        int d = ei[NEDGES + g];
        int pos = atomicAdd(&cur[d], 1);
        colv[pos] = s;
    } else if (g < NEDGES + NNODES) {
        int d = g - NEDGES;
        colv[rowp[d + 1] - 1] = d;
    }
}

// ---------------- weight transpose: fp32 [K][Nn] -> bf16 [Nn][K], LDS-tiled ----------------
__global__ void prep_w_t(const float* __restrict__ W, unsigned short* __restrict__ Wt,
                         int K, int Nn) {
    __shared__ float tile[32][33];
    const int kb = blockIdx.x * 32, nb = blockIdx.y * 32;
    const int tx = threadIdx.x & 31, ty = threadIdx.x >> 5;   // 256 thr: ty 0..7
    #pragma unroll
    for (int i = 0; i < 32; i += 8)
        tile[ty + i][tx] = W[(size_t)(kb + ty + i) * Nn + nb + tx];   // coalesced read
    __syncthreads();
    #pragma unroll
    for (int i = 0; i < 32; i += 8)
        Wt[(size_t)(nb + ty + i) * K + kb + tx] = f2bf(tile[tx][ty + i]);  // coalesced write
}

// ---------------- diffusion noise add -> bf16 ----------------
__global__ void x0_kernel(const float* __restrict__ emb, const float* __restrict__ noise,
                          const int* __restrict__ t, const float* __restrict__ sched,
                          unsigned short* __restrict__ x0b) {
    int i4 = blockIdx.x * 256 + threadIdx.x;
    if (i4 >= MPAD * (FIN / 4)) return;
    int row = i4 / (FIN / 4);
    int c = (i4 % (FIN / 4)) * 4;
    unsigned short* dst = x0b + (size_t)row * FIN + c;
    if (row < NNODES) {
        int tv = t[row];
        float sa = sched[tv], so = sched[64 + tv];
        float4 e = *(const float4*)(emb + (size_t)row * FIN + c);
        float4 nz = *(const float4*)(noise + (size_t)row * FIN + c);
        float v0 = sa * e.x + so * nz.x;
        float v1 = sa * e.y + so * nz.y;
        float v2 = sa * e.z + so * nz.z;
        float v3 = sa * e.w + so * nz.w;
        uint2 pk;
        pk.x = (unsigned)f2bf(v0) | ((unsigned)f2bf(v1) << 16);
        pk.y = (unsigned)f2bf(v2) | ((unsigned)f2bf(v3) << 16);
        *(uint2*)dst = pk;
    } else {
        uint2 pk; pk.x = 0u; pk.y = 0u;
        *(uint2*)dst = pk;
    }
}

// ---------------- pipelined bf16 MFMA GEMM (round-3 proven version) ----------------
// C[M][Nn] = A[M][K] @ Bt[Nn][K]^T + bias
// BM=256, BN=128, BK=64, 512 threads (8 waves, 4M x 2N, wave tile 64x64)
// 3-deep LDS ring, counted vmcnt, T2 xor-swizzle, T5 setprio, T1 xcd swizzle.
__device__ __forceinline__ void stage_ab(const unsigned short* __restrict__ A,
                                         const unsigned short* __restrict__ Bt,
                                         char* ldsbase, int rowBase, int colBase,
                                         int kt, int K, int tid) {
    const int r8 = tid >> 3;             // 0..63
    const int cb = (tid & 7) * 16;       // byte col within 128B row
    const size_t Kb = (size_t)K * 2;
    #pragma unroll
    for (int i = 0; i < 4; ++i) {        // A: 4 rounds x 64 rows
        int r = i * 64 + r8;
        int scb = cb ^ ((r & 7) << 4);   // inverse-swizzled source
        gload16((const char*)A + (size_t)(rowBase + r) * Kb + (size_t)kt * 2 + scb,
                ldsbase + r * 128 + cb);
    }
    #pragma unroll
    for (int i = 0; i < 2; ++i) {        // B: 2 rounds x 64 rows
        int r = i * 64 + r8;
        int scb = cb ^ ((r & 7) << 4);
        gload16((const char*)Bt + (size_t)(colBase + r) * Kb + (size_t)kt * 2 + scb,
                ldsbase + 32768 + r * 128 + cb);
    }
}

template<bool OUT_BF16>
__global__ void __launch_bounds__(512, 1)
gemm8(const unsigned short* __restrict__ A, const unsigned short* __restrict__ Bt,
      const float* __restrict__ bias, void* __restrict__ C,
      int K, int Nn, int Mstore, int gy) {
    extern __shared__ char lds[];
    const int tid = threadIdx.x;
    const int lane = tid & 63;
    const int wv = tid >> 6;          // 0..7
    const int wm = wv >> 1;           // 0..3 : 64-row block of 256
    const int wn = wv & 1;            // 0..1 : 64-col block of 128
    const int lr = lane & 15;
    const int kq = lane >> 4;

    // T1: bijective XCD swizzle (m204)
    const int total = gridDim.x;
    int lin = blockIdx.x;
    int q = total >> 3, r = total & 7;
    int xcd = lin & 7, idx = lin >> 3;
    int lin2 = (xcd < r ? xcd * (q + 1) : r * (q + 1) + (xcd - r) * q) + idx;
    const int rowBase = (lin2 / gy) * 256;
    const int colBase = (lin2 % gy) * 128;

    f32x4 acc[4][4];
    #pragma unroll
    for (int m = 0; m < 4; ++m)
        #pragma unroll
        for (int n = 0; n < 4; ++n)
            acc[m][n] = (f32x4){0.f, 0.f, 0.f, 0.f};

    const int NT = K >> 6;
    stage_ab(A, Bt, lds,               rowBase, colBase, 0,  K, tid);
    stage_ab(A, Bt, lds + RING_STRIDE, rowBase, colBase, 64, K, tid);

    for (int t = 0; t < NT; ++t) {
        // wave's own tile-t loads landed (oldest 6 of <=12 outstanding)
        if (t < NT - 1) asm volatile("s_waitcnt vmcnt(6)" ::: "memory");
        else            asm volatile("s_waitcnt vmcnt(0)" ::: "memory");
        __builtin_amdgcn_s_barrier();           // all waves' tile-t data resident
        asm volatile("" ::: "memory");
        if (t + 2 < NT)
            stage_ab(A, Bt, lds + ((t + 2) % 3) * RING_STRIDE, rowBase, colBase,
                     (t + 2) * 64, K, tid);
        const char* la = lds + (t % 3) * RING_STRIDE;
        const char* lb = la + 32768;
        #pragma unroll
        for (int k2 = 0; k2 < 2; ++k2) {
            bf16x8 fa[4], fb[4];
            #pragma unroll
            for (int m = 0; m < 4; ++m) {
                int fr = wm * 64 + m * 16 + lr;
                int off = (fr * 128 + k2 * 64 + kq * 16) ^ ((fr & 7) << 4);  // T2 swizzled read
                fa[m] = *(const bf16x8*)(la + off);
            }
            #pragma unroll
            for (int n = 0; n < 4; ++n) {
                int fr = wn * 64 + n * 16 + lr;
                int off = (fr * 128 + k2 * 64 + kq * 16) ^ ((fr & 7) << 4);
                fb[n] = *(const bf16x8*)(lb + off);
            }
            __builtin_amdgcn_s_setprio(1);
            #pragma unroll
            for (int m = 0; m < 4; ++m)
                #pragma unroll
                for (int n = 0; n < 4; ++n)
                    acc[m][n] = __builtin_amdgcn_mfma_f32_16x16x32_bf16(fa[m], fb[n], acc[m][n], 0, 0, 0);
            __builtin_amdgcn_s_setprio(0);
        }
    }

    // epilogue: col = lane&15, row = kq*4 + j
    #pragma unroll
    for (int n = 0; n < 4; ++n) {
        int col = colBase + wn * 64 + n * 16 + lr;
        float bcol = bias[col];
        #pragma unroll
        for (int m = 0; m < 4; ++m) {
            int row0 = rowBase + wm * 64 + m * 16 + kq * 4;
            #pragma unroll
            for (int j = 0; j < 4; ++j) {
                float v = acc[m][n][j] + bcol;
                if (OUT_BF16) {
                    ((unsigned short*)C)[(size_t)(row0 + j) * Nn + col] = f2bf(v);
                } else {
                    if (row0 + j < Mstore)
                        ((float*)C)[(size_t)(row0 + j) * Nn + col] = v;
                }
            }
        }
    }
}

// ---------------- GATv2 attention: one wave per destination node ----------------
// 4-edge groups (independent under fixed softmax base), f32x2 packed math,
// 2-stage group prefetch. xlr: [MPAD][2048] bf16 (xl cols [0,1024), xr cols [1024,2048)).
__global__ void __launch_bounds__(256)
attn_kernel(const unsigned short* __restrict__ xlr,
            const int* __restrict__ rowp, const int* __restrict__ colv,
            const float* __restrict__ att, const float* __restrict__ bias,
            unsigned short* __restrict__ out) {
    const int lane = threadIdx.x & 63;
    const int node = blockIdx.x * 4 + (threadIdx.x >> 6);
    const int j0 = lane * 16;

    if (node >= NNODES) {
        if (node < MPAD) {
            uint4 z; z.x = z.y = z.z = z.w = 0u;
            *(uint4*)(out + (size_t)node * D2 + j0) = z;
            *(uint4*)(out + (size_t)node * D2 + j0 + 8) = z;
        }
        return;
    }

    f32x2 attv[8], xrv[8], acc[8];
    #pragma unroll
    for (int q = 0; q < 8; ++q) attv[q] = *(const f32x2*)(att + j0 + 2 * q);
    {
        const unsigned short* xr = xlr + (size_t)node * D2X2 + D2 + j0;
        uint4 v0 = *(const uint4*)(xr);
        uint4 v1 = *(const uint4*)(xr + 8);
        unsigned u[8] = {v0.x, v0.y, v0.z, v0.w, v1.x, v1.y, v1.z, v1.w};
        #pragma unroll
        for (int q = 0; q < 8; ++q) xrv[q] = unpk2(u[q]);
    }
    #pragma unroll
    for (int q = 0; q < 8; ++q) acc[q] = (f32x2){0.f, 0.f};

    float mbase = 8.0f;     // fixed softmax base; logits O(0.2) << 8 (exact, rescale fallback kept)
    float lsum = 0.f;

    const int p0 = rowp[node], p1 = rowp[node + 1];
    const int deg = p1 - p0;
    const int ngroups = deg >> 2;

    uint4 curA[4], curB[4];
    if (ngroups > 0) {
        #pragma unroll
        for (int i = 0; i < 4; ++i) {
            int s = colv[p0 + i];
            const unsigned short* src = xlr + (size_t)s * D2X2 + j0;
            curA[i] = *(const uint4*)src;
            curB[i] = *(const uint4*)(src + 8);
        }
    }

    for (int g = 0; g < ngroups; ++g) {
        uint4 nxtA[4], nxtB[4];
        const bool more = (g + 1 < ngroups);
        if (more) {
            int base = p0 + (g + 1) * 4;
            #pragma unroll
            for (int i = 0; i < 4; ++i) {
                int s = colv[base + i];
                const unsigned short* src = xlr + (size_t)s * D2X2 + j0;
                nxtA[i] = *(const uint4*)src;
                nxtB[i] = *(const uint4*)(src + 8);
            }
        }

        // ---- logits for 4 independent edges (packed f32x2 math) ----
        float part[4];
        #pragma unroll
        for (int e = 0; e < 4; ++e) {
            unsigned uw[8] = {curA[e].x, curA[e].y, curA[e].z, curA[e].w,
                              curB[e].x, curB[e].y, curB[e].z, curB[e].w};
            f32x2 d2 = (f32x2){0.f, 0.f};
            #pragma unroll
            for (int q = 0; q < 8; ++q) {
                f32x2 s = unpk2(uw[q]) + xrv[q];
                f32x2 t = s * 0.2f;
                s.x = fmaxf(s.x, t.x);
                s.y = fmaxf(s.y, t.y);
                d2 += s * attv[q];
            }
            float pt = d2.x + d2.y;
            pt += __shfl_xor(pt, 1);
            pt += __shfl_xor(pt, 2);
            pt += __shfl_xor(pt, 4);
            pt += __shfl_xor(pt, 8);
            part[e] = pt;
        }

        float m4 = fmaxf(fmaxf(part[0], part[1]), fmaxf(part[2], part[3]));
        if (__builtin_expect(m4 > mbase, 0)) {
            float sc = __expf(mbase - m4);
            lsum *= sc;
            #pragma unroll
            for (int q = 0; q < 8; ++q) acc[q] *= sc;
            mbase = m4;
        }
        float pw[4];
        #pragma unroll
        for (int e = 0; e < 4; ++e) pw[e] = __expf(part[e] - mbase);
        lsum += (pw[0] + pw[1]) + (pw[2] + pw[3]);

        // ---- accumulate 4 edges ----
        #pragma unroll
        for (int e = 0; e < 4; ++e) {
            unsigned uw[8] = {curA[e].x, curA[e].y, curA[e].z, curA[e].w,
                              curB[e].x, curB[e].y, curB[e].z, curB[e].w};
            #pragma unroll
            for (int q = 0; q < 8; ++q)
                acc[q] += unpk2(uw[q]) * pw[e];
        }

        if (more) {
            #pragma unroll
            for (int i = 0; i < 4; ++i) { curA[i] = nxtA[i]; curB[i] = nxtB[i]; }
        }
    }

    // ---- tail (<=3 edges) ----
    for (int p = p0 + ngroups * 4; p < p1; ++p) {
        int s = colv[p];
        const unsigned short* src = xlr + (size_t)s * D2X2 + j0;
        uint4 a0 = *(const uint4*)src;
        uint4 a1 = *(const uint4*)(src + 8);
        unsigned uw[8] = {a0.x, a0.y, a0.z, a0.w, a1.x, a1.y, a1.z, a1.w};
        f32x2 d2 = (f32x2){0.f, 0.f};
        #pragma unroll
        for (int q = 0; q < 8; ++q) {
            f32x2 sv = unpk2(uw[q]) + xrv[q];
            f32x2 t = sv * 0.2f;
            sv.x = fmaxf(sv.x, t.x);
            sv.y = fmaxf(sv.y, t.y);
            d2 += sv * attv[q];
        }
        float pt = d2.x + d2.y;
        pt += __shfl_xor(pt, 1);
        pt += __shfl_xor(pt, 2);
        pt += __shfl_xor(pt, 4);
        pt += __shfl_xor(pt, 8);
        if (__builtin_expect(pt > mbase, 0)) {
            float sc = __expf(mbase - pt);
            lsum *= sc;
            #pragma unroll
            for (int q = 0; q < 8; ++q) acc[q] *= sc;
            mbase = pt;
        }
        float pw = __expf(pt - mbase);
        lsum += pw;
        #pragma unroll
        for (int q = 0; q < 8; ++q)
            acc[q] += unpk2(uw[q]) * pw;
    }

    float inv = 1.f / lsum;
    unsigned w[8];
    #pragma unroll
    for (int q = 0; q < 8; ++q) {
        float o0 = acc[q].x * inv + bias[j0 + 2 * q];
        float o1 = acc[q].y * inv + bias[j0 + 2 * q + 1];
        o0 = (o0 > 0.f) ? o0 : (__expf(o0) - 1.f);   // ELU
        o1 = (o1 > 0.f) ? o1 : (__expf(o1) - 1.f);
        w[q] = (unsigned)f2bf(o0) | ((unsigned)f2bf(o1) << 16);
    }
    uint4 v0, v1;
    v0.x = w[0]; v0.y = w[1]; v0.z = w[2]; v0.w = w[3];
    v1.x = w[4]; v1.y = w[5]; v1.z = w[6]; v1.w = w[7];
    *(uint4*)(out + (size_t)node * D2 + j0) = v0;
    *(uint4*)(out + (size_t)node * D2 + j0 + 8) = v1;
}

// ---------------- host launch ----------------
extern "C" void kernel_launch(void* const* d_in, const int* in_sizes, int n_in,
                              void* d_out, int out_size, void* d_ws, size_t ws_size,
                              hipStream_t stream) {
    const float* emb   = (const float*)d_in[0];
    const float* noise = (const float*)d_in[1];
    const int*   tarr  = (const int*)d_in[2];
    const int*   ei    = (const int*)d_in[3];
    const float* Wl1   = (const float*)d_in[4];
    const float* bl1   = (const float*)d_in[5];
    const float* Wr1   = (const float*)d_in[6];
    const float* br1   = (const float*)d_in[7];
    const float* att1  = (const float*)d_in[8];
    const float* bias1 = (const float*)d_in[9];
    const float* Wl2   = (const float*)d_in[10];
    const float* bl2   = (const float*)d_in[11];
    const float* Wr2   = (const float*)d_in[12];
    const float* br2   = (const float*)d_in[13];
    const float* att2  = (const float*)d_in[14];
    const float* bias2 = (const float*)d_in[15];
    const float* Wout  = (const float*)d_in[16];
    const float* bout  = (const float*)d_in[17];
    float* out = (float*)d_out;

    char* wsp = (char*)d_ws;
    size_t off = 0;
    auto carve = [&](size_t b) -> void* {
        void* p = wsp + off;
        off = (off + b + 255) & ~(size_t)255;
        return p;
    };
    float* sched = (float*)carve(128 * 4);
    int* cnt  = (int*)carve(NNODES * 4);
    int* rowp = (int*)carve((NNODES + 1) * 4);
    int* cur  = (int*)carve(NNODES * 4);
    int* colv = (int*)carve((NEDGES + NNODES) * 4);
    float* biasC1 = (float*)carve(D2X2 * 4);
    float* biasC2 = (float*)carve(D2X2 * 4);
    unsigned short* x0b   = (unsigned short*)carve((size_t)MPAD * FIN * 2);
    unsigned short* xlrb  = (unsigned short*)carve((size_t)MPAD * D2X2 * 2);
    unsigned short* hb    = (unsigned short*)carve((size_t)MPAD * D2 * 2);
    unsigned short* wlr1t = (unsigned short*)carve((size_t)FIN * D2X2 * 2);
    unsigned short* wlr2t = (unsigned short*)carve((size_t)D2 * D2X2 * 2);
    unsigned short* wot   = (unsigned short*)carve((size_t)D2 * FIN * 2);

    // allow 144KB dynamic LDS on the gemm kernels (host-side, idempotent)
    {
        auto* f1 = gemm8<true>;
        auto* f2 = gemm8<false>;
        hipFuncSetAttribute(reinterpret_cast<const void*>(f1),
                            hipFuncAttributeMaxDynamicSharedMemorySize, LDS_BYTES);
        hipFuncSetAttribute(reinterpret_cast<const void*>(f2),
                            hipFuncAttributeMaxDynamicSharedMemorySize, LDS_BYTES);
    }

    hipMemsetAsync(cnt, 0, NNODES * 4, stream);
    csr_count<<<(NEDGES + 255) / 256, 256, 0, stream>>>(ei, cnt);
    csr_scan<<<1, 1024, 0, stream>>>(cnt, rowp, cur, sched);
    csr_fill<<<(NEDGES + NNODES + 255) / 256, 256, 0, stream>>>(ei, rowp, cur, colv);

    // combined biases via d2d async copies
    hipMemcpyAsync(biasC1,      bl1, D2 * 4, hipMemcpyDeviceToDevice, stream);
    hipMemcpyAsync(biasC1 + D2, br1, D2 * 4, hipMemcpyDeviceToDevice, stream);
    hipMemcpyAsync(biasC2,      bl2, D2 * 4, hipMemcpyDeviceToDevice, stream);
    hipMemcpyAsync(biasC2 + D2, br2, D2 * 4, hipMemcpyDeviceToDevice, stream);

    // combined transposed weights: rows [0,1024) = Wl, rows [1024,2048) = Wr
    {
        dim3 b(256);
        prep_w_t<<<dim3(FIN / 32, D2 / 32), b, 0, stream>>>(Wl1, wlr1t, FIN, D2);
        prep_w_t<<<dim3(FIN / 32, D2 / 32), b, 0, stream>>>(Wr1, wlr1t + (size_t)D2 * FIN, FIN, D2);
        prep_w_t<<<dim3(D2 / 32, D2 / 32),  b, 0, stream>>>(Wl2, wlr2t, D2, D2);
        prep_w_t<<<dim3(D2 / 32, D2 / 32),  b, 0, stream>>>(Wr2, wlr2t + (size_t)D2 * D2, D2, D2);
        prep_w_t<<<dim3(D2 / 32, FIN / 32), b, 0, stream>>>(Wout, wot, D2, FIN);
    }

    x0_kernel<<<(MPAD * (FIN / 4)) / 256, 256, 0, stream>>>(emb, noise, tarr, sched, x0b);

    // layer 1 fused GEMM: [MPAD x 768] @ [768 x 2048] -> xlrb
    gemm8<true><<<dim3((MPAD / 256) * (D2X2 / 128)), 512, LDS_BYTES, stream>>>(
        x0b, wlr1t, biasC1, xlrb, FIN, D2X2, MPAD, D2X2 / 128);
    attn_kernel<<<MPAD / 4, 256, 0, stream>>>(xlrb, rowp, colv, att1, bias1, hb);

    // layer 2 fused GEMM: [MPAD x 1024] @ [1024 x 2048] -> xlrb
    gemm8<true><<<dim3((MPAD / 256) * (D2X2 / 128)), 512, LDS_BYTES, stream>>>(
        hb, wlr2t, biasC2, xlrb, D2, D2X2, MPAD, D2X2 / 128);
    attn_kernel<<<MPAD / 4, 256, 0, stream>>>(xlrb, rowp, colv, att2, bias2, hb);

    // output GEMM: [MPAD x 1024] @ [1024 x 768] -> fp32 d_out (guarded rows)
    gemm8<false><<<dim3((MPAD / 256) * (FIN / 128)), 512, LDS_BYTES, stream>>>(
        hb, wot, bout, out, D2, FIN, NNODES, FIN / 128);

    (void)in_sizes; (void)n_in; (void)out_size; (void)ws_size;
}

// Round 7
// 335.311 us; speedup vs baseline: 1.1421x; 1.0855x over previous
//
#include <hip/hip_runtime.h>

#define NNODES 10000
#define NEDGES 160000
#define MPAD   10240      // 80 * 128
#define FIN    768
#define D2     1024
#define D2X2   2048
#define TSTEPS 50

typedef __bf16 bf16x8 __attribute__((ext_vector_type(8)));
typedef float  f32x4  __attribute__((ext_vector_type(4)));
typedef float  f32x2  __attribute__((ext_vector_type(2)));

__device__ __forceinline__ unsigned short f2bf(float f) {
    unsigned u = __builtin_bit_cast(unsigned, f);
    u += 0x7FFFu + ((u >> 16) & 1u);
    return (unsigned short)(u >> 16);
}
__device__ __forceinline__ f32x2 unpk2(unsigned u) {
    f32x2 r;
    r.x = __builtin_bit_cast(float, u << 16);
    r.y = __builtin_bit_cast(float, u & 0xFFFF0000u);
    return r;
}
__device__ __forceinline__ void gload16(const void* g, void* l) {
    __builtin_amdgcn_global_load_lds((const __attribute__((address_space(1))) void*)g,
                                     (__attribute__((address_space(3))) void*)l, 16, 0, 0);
}

// ---------------- CSR: count ----------------
__global__ void csr_count(const int* __restrict__ ei, int* cnt) {
    int g = blockIdx.x * 256 + threadIdx.x;
    if (g < NEDGES) atomicAdd(&cnt[ei[NEDGES + g]], 1);
}
// ---------------- CSR: scan (+ cosine schedule fold-in) ----------------
__global__ void csr_scan(const int* __restrict__ cnt, int* rowp, int* cur, float* sched) {
    if (threadIdx.x == 0) {
        const double PI = 3.14159265358979323846;
        double acp = 1.0;
        for (int i = 0; i < TSTEPS; ++i) {
            double x0 = (double)i / (double)TSTEPS;
            double x1 = (double)(i + 1) / (double)TSTEPS;
            double c0 = cos((x0 + 0.008) / 1.008 * PI * 0.5);
            double c1 = cos((x1 + 0.008) / 1.008 * PI * 0.5);
            double a0 = c0 * c0, a1 = c1 * c1;
            double beta = 1.0 - a1 / a0;
            if (beta < 0.0) beta = 0.0;
            if (beta > 0.999) beta = 0.999;
            acp *= (1.0 - beta);
            sched[i]      = (float)sqrt(acp);
            sched[64 + i] = (float)sqrt(1.0 - acp);
        }
    }
    __shared__ int part[1024];
    int tid = threadIdx.x;
    const int per = 10;
    int base = tid * per;
    int local[per];
    int s = 0;
    #pragma unroll
    for (int i = 0; i < per; ++i) {
        int idx = base + i;
        int v = (idx < NNODES) ? (cnt[idx] + 1) : 0;   // +1 = self loop
        local[i] = s;
        s += v;
    }
    part[tid] = s;
    __syncthreads();
    for (int off = 1; off < 1024; off <<= 1) {
        int v = (tid >= off) ? part[tid - off] : 0;
        __syncthreads();
        part[tid] += v;
        __syncthreads();
    }
    int offset = (tid > 0) ? part[tid - 1] : 0;
    #pragma unroll
    for (int i = 0; i < per; ++i) {
        int idx = base + i;
        if (idx < NNODES) {
            int v = offset + local[i];
            rowp[idx] = v;
            cur[idx]  = v;
        } else if (idx == NNODES) {
            rowp[NNODES] = offset + local[i];
        }
    }
}
// ---------------- CSR: fill (self loop at fixed last slot) ----------------
__global__ void csr_fill(const int* __restrict__ ei, const int* __restrict__ rowp,
                         int* cur, int* colv) {
    int g = blockIdx.x * 256 + threadIdx.x;
    if (g < NEDGES) {
        int s = ei[g];
        int d = ei[NEDGES + g];
        int pos = atomicAdd(&cur[d], 1);
        colv[pos] = s;
    } else if (g < NEDGES + NNODES) {
        int d = g - NEDGES;
        colv[rowp[d + 1] - 1] = d;
    }
}

// ---------------- unified weight transpose: 5 jobs, fp32 [K][N] -> bf16 [N][K] ----------------
struct TJ { const float* W; unsigned short* out; int K; int N; int end; };
struct TJ5 { TJ j[5]; };
__global__ void __launch_bounds__(256)
prep_all(TJ5 js) {
    int b = blockIdx.x;
    int i = 0;
    #pragma unroll
    for (int k = 0; k < 5; ++k) if (b >= js.j[k].end) i = k + 1;
    TJ p = js.j[i];
    int start = (i > 0) ? js.j[i - 1].end : 0;
    int lt = b - start;
    int kt = p.K >> 5;                 // tiles along K
    int kb = (lt % kt) * 32;
    int nb = (lt / kt) * 32;
    __shared__ float tile[32][33];
    const int tx = threadIdx.x & 31, ty = threadIdx.x >> 5;   // ty 0..7
    #pragma unroll
    for (int r = 0; r < 32; r += 8)
        tile[ty + r][tx] = p.W[(size_t)(kb + ty + r) * p.N + nb + tx];   // coalesced read
    __syncthreads();
    #pragma unroll
    for (int r = 0; r < 32; r += 8)
        p.out[(size_t)(nb + ty + r) * p.K + kb + tx] = f2bf(tile[tx][ty + r]);  // coalesced write
}

// ---------------- diffusion noise add -> bf16 ----------------
__global__ void x0_kernel(const float* __restrict__ emb, const float* __restrict__ noise,
                          const int* __restrict__ t, const float* __restrict__ sched,
                          unsigned short* __restrict__ x0b) {
    int i4 = blockIdx.x * 256 + threadIdx.x;
    if (i4 >= MPAD * (FIN / 4)) return;
    int row = i4 / (FIN / 4);
    int c = (i4 % (FIN / 4)) * 4;
    unsigned short* dst = x0b + (size_t)row * FIN + c;
    if (row < NNODES) {
        int tv = t[row];
        float sa = sched[tv], so = sched[64 + tv];
        float4 e = *(const float4*)(emb + (size_t)row * FIN + c);
        float4 nz = *(const float4*)(noise + (size_t)row * FIN + c);
        float v0 = sa * e.x + so * nz.x;
        float v1 = sa * e.y + so * nz.y;
        float v2 = sa * e.z + so * nz.z;
        float v3 = sa * e.w + so * nz.w;
        uint2 pk;
        pk.x = (unsigned)f2bf(v0) | ((unsigned)f2bf(v1) << 16);
        pk.y = (unsigned)f2bf(v2) | ((unsigned)f2bf(v3) << 16);
        *(uint2*)dst = pk;
    } else {
        uint2 pk; pk.x = 0u; pk.y = 0u;
        *(uint2*)dst = pk;
    }
}

// ---------------- m97-style bf16 MFMA GEMM: 128x128, BK=64, single-buffer 2-barrier ----------------
// C[M][Nn] = A[M][K] @ Bt[Nn][K]^T + bias(two-pointer).  256 thr (4 waves 2Mx2N, wave tile 64x64).
// T2 both-sides swizzle (0 conflicts, r3-proven), T1 bijective XCD swizzle, T5 setprio.
// 32 KB LDS + ~100 VGPR -> 4-5 blocks/CU co-resident: cross-block overlap hides barrier drains (m114).
template<bool OUT_BF16>
__global__ void __launch_bounds__(256)
gemmM(const unsigned short* __restrict__ A, const unsigned short* __restrict__ Bt,
      const float* __restrict__ bl, const float* __restrict__ br, void* __restrict__ C,
      int K, int Nn, int Mstore, int gy) {
    __shared__ __align__(16) unsigned short As[128 * 64];   // 16 KB
    __shared__ __align__(16) unsigned short Bs[128 * 64];   // 16 KB

    const int tid = threadIdx.x;
    const int lane = tid & 63;
    const int wv = tid >> 6;          // 0..3
    const int wm = wv >> 1;           // 0..1
    const int wn = wv & 1;            // 0..1
    const int lr = lane & 15;
    const int kq = lane >> 4;

    // T1: bijective XCD swizzle (m204)
    const int total = gridDim.x;
    int lin = blockIdx.x;
    int q = total >> 3, r = total & 7;
    int xcd = lin & 7, idx = lin >> 3;
    int lin2 = (xcd < r ? xcd * (q + 1) : r * (q + 1) + (xcd - r) * q) + idx;
    const int rowBase = (lin2 / gy) * 128;
    const int colBase = (lin2 % gy) * 128;

    f32x4 acc[4][4];
    #pragma unroll
    for (int m = 0; m < 4; ++m)
        #pragma unroll
        for (int n = 0; n < 4; ++n)
            acc[m][n] = (f32x4){0.f, 0.f, 0.f, 0.f};

    const int r8 = tid >> 3;          // 0..31
    const int cb = (tid & 7) * 16;    // byte col in 128B row
    const size_t Kb = (size_t)K * 2;
    const int NT = K >> 6;

    for (int t = 0; t < NT; ++t) {
        // stage tile t: A 128x64 + B 128x64, 4 rounds x 32 rows each
        const size_t kOff = (size_t)(t * 64) * 2;
        #pragma unroll
        for (int i = 0; i < 4; ++i) {
            int rr = i * 32 + r8;
            int scb = cb ^ ((rr & 7) << 4);     // inverse-swizzled global source
            gload16((const char*)A + (size_t)(rowBase + rr) * Kb + kOff + scb,
                    (char*)As + rr * 128 + cb);
            gload16((const char*)Bt + (size_t)(colBase + rr) * Kb + kOff + scb,
                    (char*)Bs + rr * 128 + cb);
        }
        __syncthreads();                        // drains vmcnt(0): tile resident

        #pragma unroll
        for (int k2 = 0; k2 < 2; ++k2) {
            bf16x8 fa[4], fb[4];
            #pragma unroll
            for (int m = 0; m < 4; ++m) {
                int fr = wm * 64 + m * 16 + lr;
                int off = (fr * 128 + k2 * 64 + kq * 16) ^ ((fr & 7) << 4);  // T2 swizzled read
                fa[m] = *(const bf16x8*)((const char*)As + off);
            }
            #pragma unroll
            for (int n = 0; n < 4; ++n) {
                int fr = wn * 64 + n * 16 + lr;
                int off = (fr * 128 + k2 * 64 + kq * 16) ^ ((fr & 7) << 4);
                fb[n] = *(const bf16x8*)((const char*)Bs + off);
            }
            __builtin_amdgcn_s_setprio(1);
            #pragma unroll
            for (int m = 0; m < 4; ++m)
                #pragma unroll
                for (int n = 0; n < 4; ++n)
                    acc[m][n] = __builtin_amdgcn_mfma_f32_16x16x32_bf16(fa[m], fb[n], acc[m][n], 0, 0, 0);
            __builtin_amdgcn_s_setprio(0);
        }
        __syncthreads();                        // all reads done before next overwrite
    }

    // epilogue: col = lane&15, row = kq*4 + j
    #pragma unroll
    for (int n = 0; n < 4; ++n) {
        int col = colBase + wn * 64 + n * 16 + lr;
        float bcol = (col < D2) ? bl[col] : br[col - D2];
        #pragma unroll
        for (int m = 0; m < 4; ++m) {
            int row0 = rowBase + wm * 64 + m * 16 + kq * 4;
            #pragma unroll
            for (int j = 0; j < 4; ++j) {
                float v = acc[m][n][j] + bcol;
                if (OUT_BF16) {
                    ((unsigned short*)C)[(size_t)(row0 + j) * Nn + col] = f2bf(v);
                } else {
                    if (row0 + j < Mstore)
                        ((float*)C)[(size_t)(row0 + j) * Nn + col] = v;
                }
            }
        }
    }
}

// ---------------- GATv2 attention: one wave per destination node (round-6 proven) ----------------
__global__ void __launch_bounds__(256)
attn_kernel(const unsigned short* __restrict__ xlr,
            const int* __restrict__ rowp, const int* __restrict__ colv,
            const float* __restrict__ att, const float* __restrict__ bias,
            unsigned short* __restrict__ out) {
    const int lane = threadIdx.x & 63;
    const int node = blockIdx.x * 4 + (threadIdx.x >> 6);
    const int j0 = lane * 16;

    if (node >= NNODES) {
        if (node < MPAD) {
            uint4 z; z.x = z.y = z.z = z.w = 0u;
            *(uint4*)(out + (size_t)node * D2 + j0) = z;
            *(uint4*)(out + (size_t)node * D2 + j0 + 8) = z;
        }
        return;
    }

    f32x2 attv[8], xrv[8], acc[8];
    #pragma unroll
    for (int q = 0; q < 8; ++q) attv[q] = *(const f32x2*)(att + j0 + 2 * q);
    {
        const unsigned short* xr = xlr + (size_t)node * D2X2 + D2 + j0;
        uint4 v0 = *(const uint4*)(xr);
        uint4 v1 = *(const uint4*)(xr + 8);
        unsigned u[8] = {v0.x, v0.y, v0.z, v0.w, v1.x, v1.y, v1.z, v1.w};
        #pragma unroll
        for (int q = 0; q < 8; ++q) xrv[q] = unpk2(u[q]);
    }
    #pragma unroll
    for (int q = 0; q < 8; ++q) acc[q] = (f32x2){0.f, 0.f};

    float mbase = 8.0f;     // fixed softmax base; rescale fallback keeps exactness
    float lsum = 0.f;

    const int p0 = rowp[node], p1 = rowp[node + 1];
    const int deg = p1 - p0;
    const int ngroups = deg >> 2;

    uint4 curA[4], curB[4];
    if (ngroups > 0) {
        #pragma unroll
        for (int i = 0; i < 4; ++i) {
            int s = colv[p0 + i];
            const unsigned short* src = xlr + (size_t)s * D2X2 + j0;
            curA[i] = *(const uint4*)src;
            curB[i] = *(const uint4*)(src + 8);
        }
    }

    for (int g = 0; g < ngroups; ++g) {
        uint4 nxtA[4], nxtB[4];
        const bool more = (g + 1 < ngroups);
        if (more) {
            int base = p0 + (g + 1) * 4;
            #pragma unroll
            for (int i = 0; i < 4; ++i) {
                int s = colv[base + i];
                const unsigned short* src = xlr + (size_t)s * D2X2 + j0;
                nxtA[i] = *(const uint4*)src;
                nxtB[i] = *(const uint4*)(src + 8);
            }
        }

        float part[4];
        #pragma unroll
        for (int e = 0; e < 4; ++e) {
            unsigned uw[8] = {curA[e].x, curA[e].y, curA[e].z, curA[e].w,
                              curB[e].x, curB[e].y, curB[e].z, curB[e].w};
            f32x2 d2 = (f32x2){0.f, 0.f};
            #pragma unroll
            for (int q = 0; q < 8; ++q) {
                f32x2 s = unpk2(uw[q]) + xrv[q];
                f32x2 t = s * 0.2f;
                s.x = fmaxf(s.x, t.x);
                s.y = fmaxf(s.y, t.y);
                d2 += s * attv[q];
            }
            float pt = d2.x + d2.y;
            pt += __shfl_xor(pt, 1);
            pt += __shfl_xor(pt, 2);
            pt += __shfl_xor(pt, 4);
            pt += __shfl_xor(pt, 8);
            part[e] = pt;
        }

        float m4 = fmaxf(fmaxf(part[0], part[1]), fmaxf(part[2], part[3]));
        if (__builtin_expect(m4 > mbase, 0)) {
            float sc = __expf(mbase - m4);
            lsum *= sc;
            #pragma unroll
            for (int q = 0; q < 8; ++q) acc[q] *= sc;
            mbase = m4;
        }
        float pw[4];
        #pragma unroll
        for (int e = 0; e < 4; ++e) pw[e] = __expf(part[e] - mbase);
        lsum += (pw[0] + pw[1]) + (pw[2] + pw[3]);

        #pragma unroll
        for (int e = 0; e < 4; ++e) {
            unsigned uw[8] = {curA[e].x, curA[e].y, curA[e].z, curA[e].w,
                              curB[e].x, curB[e].y, curB[e].z, curB[e].w};
            #pragma unroll
            for (int q = 0; q < 8; ++q)
                acc[q] += unpk2(uw[q]) * pw[e];
        }

        if (more) {
            #pragma unroll
            for (int i = 0; i < 4; ++i) { curA[i] = nxtA[i]; curB[i] = nxtB[i]; }
        }
    }

    for (int p = p0 + ngroups * 4; p < p1; ++p) {
        int s = colv[p];
        const unsigned short* src = xlr + (size_t)s * D2X2 + j0;
        uint4 a0 = *(const uint4*)src;
        uint4 a1 = *(const uint4*)(src + 8);
        unsigned uw[8] = {a0.x, a0.y, a0.z, a0.w, a1.x, a1.y, a1.z, a1.w};
        f32x2 d2 = (f32x2){0.f, 0.f};
        #pragma unroll
        for (int q = 0; q < 8; ++q) {
            f32x2 sv = unpk2(uw[q]) + xrv[q];
            f32x2 t = sv * 0.2f;
            sv.x = fmaxf(sv.x, t.x);
            sv.y = fmaxf(sv.y, t.y);
            d2 += sv * attv[q];
        }
        float pt = d2.x + d2.y;
        pt += __shfl_xor(pt, 1);
        pt += __shfl_xor(pt, 2);
        pt += __shfl_xor(pt, 4);
        pt += __shfl_xor(pt, 8);
        if (__builtin_expect(pt > mbase, 0)) {
            float sc = __expf(mbase - pt);
            lsum *= sc;
            #pragma unroll
            for (int q = 0; q < 8; ++q) acc[q] *= sc;
            mbase = pt;
        }
        float pw = __expf(pt - mbase);
        lsum += pw;
        #pragma unroll
        for (int q = 0; q < 8; ++q)
            acc[q] += unpk2(uw[q]) * pw;
    }

    float inv = 1.f / lsum;
    unsigned w[8];
    #pragma unroll
    for (int q = 0; q < 8; ++q) {
        float o0 = acc[q].x * inv + bias[j0 + 2 * q];
        float o1 = acc[q].y * inv + bias[j0 + 2 * q + 1];
        o0 = (o0 > 0.f) ? o0 : (__expf(o0) - 1.f);   // ELU
        o1 = (o1 > 0.f) ? o1 : (__expf(o1) - 1.f);
        w[q] = (unsigned)f2bf(o0) | ((unsigned)f2bf(o1) << 16);
    }
    uint4 v0, v1;
    v0.x = w[0]; v0.y = w[1]; v0.z = w[2]; v0.w = w[3];
    v1.x = w[4]; v1.y = w[5]; v1.z = w[6]; v1.w = w[7];
    *(uint4*)(out + (size_t)node * D2 + j0) = v0;
    *(uint4*)(out + (size_t)node * D2 + j0 + 8) = v1;
}

// ---------------- host launch ----------------
extern "C" void kernel_launch(void* const* d_in, const int* in_sizes, int n_in,
                              void* d_out, int out_size, void* d_ws, size_t ws_size,
                              hipStream_t stream) {
    const float* emb   = (const float*)d_in[0];
    const float* noise = (const float*)d_in[1];
    const int*   tarr  = (const int*)d_in[2];
    const int*   ei    = (const int*)d_in[3];
    const float* Wl1   = (const float*)d_in[4];
    const float* bl1   = (const float*)d_in[5];
    const float* Wr1   = (const float*)d_in[6];
    const float* br1   = (const float*)d_in[7];
    const float* att1  = (const float*)d_in[8];
    const float* bias1 = (const float*)d_in[9];
    const float* Wl2   = (const float*)d_in[10];
    const float* bl2   = (const float*)d_in[11];
    const float* Wr2   = (const float*)d_in[12];
    const float* br2   = (const float*)d_in[13];
    const float* att2  = (const float*)d_in[14];
    const float* bias2 = (const float*)d_in[15];
    const float* Wout  = (const float*)d_in[16];
    const float* bout  = (const float*)d_in[17];
    float* out = (float*)d_out;

    char* wsp = (char*)d_ws;
    size_t off = 0;
    auto carve = [&](size_t b) -> void* {
        void* p = wsp + off;
        off = (off + b + 255) & ~(size_t)255;
        return p;
    };
    float* sched = (float*)carve(128 * 4);
    int* cnt  = (int*)carve(NNODES * 4);
    int* rowp = (int*)carve((NNODES + 1) * 4);
    int* cur  = (int*)carve(NNODES * 4);
    int* colv = (int*)carve((NEDGES + NNODES) * 4);
    unsigned short* x0b   = (unsigned short*)carve((size_t)MPAD * FIN * 2);
    unsigned short* xlrb  = (unsigned short*)carve((size_t)MPAD * D2X2 * 2);
    unsigned short* hb    = (unsigned short*)carve((size_t)MPAD * D2 * 2);
    unsigned short* wlr1t = (unsigned short*)carve((size_t)FIN * D2X2 * 2);
    unsigned short* wlr2t = (unsigned short*)carve((size_t)D2 * D2X2 * 2);
    unsigned short* wot   = (unsigned short*)carve((size_t)D2 * FIN * 2);

    hipMemsetAsync(cnt, 0, NNODES * 4, stream);
    csr_count<<<(NEDGES + 255) / 256, 256, 0, stream>>>(ei, cnt);
    csr_scan<<<1, 1024, 0, stream>>>(cnt, rowp, cur, sched);
    csr_fill<<<(NEDGES + NNODES + 255) / 256, 256, 0, stream>>>(ei, rowp, cur, colv);

    // one kernel: 5 weight transposes (tile counts: 768,768,1024,1024,768 -> ends cumulative)
    {
        TJ5 js;
        js.j[0] = {Wl1,  wlr1t,                         FIN, D2,  768};
        js.j[1] = {Wr1,  wlr1t + (size_t)D2 * FIN,      FIN, D2,  1536};
        js.j[2] = {Wl2,  wlr2t,                         D2,  D2,  2560};
        js.j[3] = {Wr2,  wlr2t + (size_t)D2 * D2,       D2,  D2,  3584};
        js.j[4] = {Wout, wot,                           D2,  FIN, 4352};
        prep_all<<<4352, 256, 0, stream>>>(js);
    }

    x0_kernel<<<(MPAD * (FIN / 4)) / 256, 256, 0, stream>>>(emb, noise, tarr, sched, x0b);

    // layer 1 fused GEMM: [MPAD x 768] @ [768 x 2048] -> xlrb
    gemmM<true><<<dim3((MPAD / 128) * (D2X2 / 128)), 256, 0, stream>>>(
        x0b, wlr1t, bl1, br1, xlrb, FIN, D2X2, MPAD, D2X2 / 128);
    attn_kernel<<<MPAD / 4, 256, 0, stream>>>(xlrb, rowp, colv, att1, bias1, hb);

    // layer 2 fused GEMM: [MPAD x 1024] @ [1024 x 2048] -> xlrb
    gemmM<true><<<dim3((MPAD / 128) * (D2X2 / 128)), 256, 0, stream>>>(
        hb, wlr2t, bl2, br2, xlrb, D2, D2X2, MPAD, D2X2 / 128);
    attn_kernel<<<MPAD / 4, 256, 0, stream>>>(xlrb, rowp, colv, att2, bias2, hb);

    // output GEMM: [MPAD x 1024] @ [1024 x 768] -> fp32 d_out (guarded rows; Nn<1024 so bl used)
    gemmM<false><<<dim3((MPAD / 128) * (FIN / 128)), 256, 0, stream>>>(
        hb, wot, bout, bout, out, D2, FIN, NNODES, FIN / 128);

    (void)in_sizes; (void)n_in; (void)out_size; (void)ws_size;
}